// Round 7
// baseline (1153.592 us; speedup 1.0000x reference)
//
#include <hip/hip_runtime.h>
#include <hip/hip_cooperative_groups.h>
#include <math.h>

namespace cg = cooperative_groups;

#define NLVL  16
#define TSZ   (1u << 19)
#define TMASK (TSZ - 1u)

struct ResArr { int m1[NLVL * 4]; };  // per level, per dim: res-1

typedef short  short8  __attribute__((ext_vector_type(8)));
typedef float  float4v __attribute__((ext_vector_type(4)));

static __device__ __forceinline__ unsigned short f2bf(float f) {
    unsigned u = __float_as_uint(f);
    return (unsigned short)((u + 0x7fffu + ((u >> 16) & 1u)) >> 16);  // RNE
}

// ---------------------------------------------------------------------------
// Encode body, bf16-table version (verified r2-r6: ~96% of the L2
// request-service roofline at ~10 req/point-level). Guard is non-returning
// so this can sit inside a grid-stride unit loop.
// ---------------------------------------------------------------------------
static __device__ __forceinline__
void encode_point_bf16(const float4*   __restrict__ x,
                       const unsigned* __restrict__ tbl,     // [NLVL][TSZ] bf16 pairs
                       unsigned*       __restrict__ featbf,  // [NLVL][N] bf16 pairs
                       int N, int l, int n, const ResArr& res)
{
    if (n < N) {
        const float4 xv = x[n];
        const float px[4] = {xv.x, xv.y, xv.z, xv.w};

        int   bi[4];
        float fr[4], om[4];
        #pragma unroll
        for (int d = 0; d < 4; ++d) {
            const int r = res.m1[l * 4 + d];       // wave-uniform -> scalar
            const float pos = px[d] * (float)r;
            const float fb  = floorf(pos);
            fr[d] = pos - fb;
            om[d] = 1.0f - fr[d];
            bi[d] = (int)fb;
        }
        const unsigned* tl  = tbl + (size_t)l * TSZ;
        const uint2*    tl2 = (const uint2*)tl;
        const uint4*    tl4 = (const uint4*)tl;

        unsigned hrest[8];
        #pragma unroll
        for (int p = 0; p < 8; ++p) {
            const int c1 = bi[1] + ( p       & 1);
            const int c2 = bi[2] + ((p >> 1) & 1);
            const int c3 = bi[3] + ((p >> 2) & 1);
            hrest[p] = ((unsigned)c1 * 2654435761u)
                     ^ ((unsigned)c2 * 805459861u)
                     ^ ((unsigned)c3 * 3674653429u);
        }

        const int b0 = bi[0];
        unsigned ea[8], eb[8];   // packed bf16 pairs: dim0-offset 0 / offset 1

        if ((b0 & 1) == 0) {
            // bi0 even: partner index = h ^ 1 -> one aligned 8B load per pair
            #pragma unroll
            for (int p = 0; p < 8; ++p) {
                const unsigned h = ((unsigned)b0 ^ hrest[p]) & TMASK;
                const uint2 q = tl2[h >> 1];
                ea[p] = (h & 1u) ? q.y : q.x;
                eb[p] = (h & 1u) ? q.x : q.y;
            }
        } else if ((b0 & 3) == 1) {
            // bi0 % 4 == 1: partner = h ^ 3 -> same aligned 16B group
            #pragma unroll
            for (int p = 0; p < 8; ++p) {
                const unsigned hA = ((unsigned)b0 ^ hrest[p]) & TMASK;
                const uint4 q = tl4[hA >> 2];
                const unsigned jA  = hA & 3u;
                const unsigned loA = (jA & 2u) ? q.z : q.x;
                const unsigned hiA = (jA & 2u) ? q.w : q.y;
                const unsigned loB = (jA & 2u) ? q.x : q.z;
                const unsigned hiB = (jA & 2u) ? q.y : q.w;
                ea[p] = (jA & 1u) ? hiA : loA;
                eb[p] = (jA & 1u) ? loB : hiB;
            }
        } else {
            // bi0 % 4 == 3: partner differs in >= 3 low bits -> two 4B loads
            #pragma unroll
            for (int p = 0; p < 8; ++p) {
                const unsigned hA = ((unsigned)b0       ^ hrest[p]) & TMASK;
                const unsigned hB = ((unsigned)(b0 + 1) ^ hrest[p]) & TMASK;
                ea[p] = tl[hA];
                eb[p] = tl[hB];
            }
        }

        float2 fv[16];   // fv[2p] = dim0-offset 0, fv[2p+1] = dim0-offset 1
        #pragma unroll
        for (int p = 0; p < 8; ++p) {
            fv[2 * p]     = make_float2(__uint_as_float(ea[p] << 16),
                                        __uint_as_float(ea[p] & 0xffff0000u));
            fv[2 * p + 1] = make_float2(__uint_as_float(eb[p] << 16),
                                        __uint_as_float(eb[p] & 0xffff0000u));
        }

        float wt[16];
        #pragma unroll
        for (int c = 0; c < 16; ++c) {
            float w = ( c       & 1) ? fr[0] : om[0];
            w      *= ((c >> 1) & 1) ? fr[1] : om[1];
            w      *= ((c >> 2) & 1) ? fr[2] : om[2];
            w      *= ((c >> 3) & 1) ? fr[3] : om[3];
            wt[c] = w;
        }

        float a0 = 0.0f, a1 = 0.0f;
        #pragma unroll
        for (int c = 0; c < 16; ++c) {       // same order as reference einsum
            a0 = fmaf(wt[c], fv[c].x, a0);
            a1 = fmaf(wt[c], fv[c].y, a1);
        }
        featbf[(size_t)l * N + n] = (unsigned)f2bf(a0) | ((unsigned)f2bf(a1) << 16);
    }
}

// ---------------------------------------------------------------------------
// COOPERATIVE cvt+encode (round 7): one dispatch, persistent grid-stride
// blocks. Phase 1 converts the f32 table to packed bf16 pairs; grid.sync();
// phase 2 encodes the (level, chunk) units in level-major grid-stride order
// (concurrent window = gridDim units ~ half a level -> per-level L2
// residency preserved). Removes the cvt dispatch + gap and the 65536-block
// launch/drain churn of the old encode (~28 us above its request floor).
// Same register class as plain encode (~32-40 VGPR) -> no regalloc coupling
// (the r1/r5 failure mode). MLP stays a separate kernel image.
// ---------------------------------------------------------------------------
__global__ __launch_bounds__(256, 8)
void ingp_cvt_encode(const float4*   __restrict__ x,
                     const float4*   __restrict__ table4,   // f32 table as float4
                     unsigned*       __restrict__ tblbf,
                     unsigned*       __restrict__ featbf,
                     int N, int chunksPerLevel, int totalUnits, ResArr res)
{
    const int tid = (int)threadIdx.x;
    const int gsz = (int)gridDim.x * 256;

    // ---- phase 1: f32 pairs -> packed bf16 pairs ----
    {
        uint2* o = (uint2*)tblbf;
        const int totalPairs = (int)(NLVL * TSZ / 2);
        for (int i = (int)blockIdx.x * 256 + tid; i < totalPairs; i += gsz) {
            const float4 e = table4[i];
            o[i] = make_uint2((unsigned)f2bf(e.x) | ((unsigned)f2bf(e.y) << 16),
                              (unsigned)f2bf(e.z) | ((unsigned)f2bf(e.w) << 16));
        }
    }
    __threadfence();
    cg::this_grid().sync();

    // ---- phase 2: encode, level-major grid-stride over units ----
    for (int u = (int)blockIdx.x; u < totalUnits; u += (int)gridDim.x) {
        const int l     = u / chunksPerLevel;
        const int chunk = u - l * chunksPerLevel;
        encode_point_bf16(x, tblbf, featbf, N, l, chunk * 256 + tid, res);
    }
}

// ---------------------------------------------------------------------------
// Non-cooperative fallbacks (r6-verified path).
// ---------------------------------------------------------------------------
__global__ __launch_bounds__(256)
void cvt_table(const float4* __restrict__ t, uint2* __restrict__ o, int totalPairs)
{
    for (int i = blockIdx.x * 256 + (int)threadIdx.x; i < totalPairs;
         i += gridDim.x * 256) {
        const float4 e = t[i];
        o[i] = make_uint2((unsigned)f2bf(e.x) | ((unsigned)f2bf(e.y) << 16),
                          (unsigned)f2bf(e.z) | ((unsigned)f2bf(e.w) << 16));
    }
}

__global__ __launch_bounds__(256, 4)
void ingp_encode_bf16(const float4*   __restrict__ x,
                      const unsigned* __restrict__ tbl,
                      unsigned*       __restrict__ featbf,
                      int N, int chunksPerLevel, ResArr res)
{
    const int l     = blockIdx.x / chunksPerLevel;
    const int chunk = blockIdx.x - l * chunksPerLevel;
    encode_point_bf16(x, tbl, featbf, N, l, chunk * 256 + (int)threadIdx.x, res);
}

// f32-table encode (fallback when ws can't hold the bf16 table copy).
static __device__ __forceinline__
void encode_point_f32(const float4* __restrict__ x,
                      const float2* __restrict__ table,
                      unsigned*     __restrict__ featbf,
                      int N, int l, int n, const ResArr& res)
{
    if (n >= N) return;

    const float4 xv = x[n];
    const float px[4] = {xv.x, xv.y, xv.z, xv.w};

    int   bi[4];
    float fr[4], om[4];
    #pragma unroll
    for (int d = 0; d < 4; ++d) {
        const int r = res.m1[l * 4 + d];
        const float pos = px[d] * (float)r;
        const float fb  = floorf(pos);
        fr[d] = pos - fb;
        om[d] = 1.0f - fr[d];
        bi[d] = (int)fb;
    }
    const float2* tl  = table + (size_t)l * TSZ;
    const float4* tl4 = (const float4*)tl;

    unsigned hrest[8];
    #pragma unroll
    for (int p = 0; p < 8; ++p) {
        const int c1 = bi[1] + ( p       & 1);
        const int c2 = bi[2] + ((p >> 1) & 1);
        const int c3 = bi[3] + ((p >> 2) & 1);
        hrest[p] = ((unsigned)c1 * 2654435761u)
                 ^ ((unsigned)c2 * 805459861u)
                 ^ ((unsigned)c3 * 3674653429u);
    }

    float2 fv[16];
    if ((bi[0] & 1) == 0) {
        #pragma unroll
        for (int p = 0; p < 8; ++p) {
            const unsigned h = ((unsigned)bi[0] ^ hrest[p]) & TMASK;
            const float4 q = tl4[h >> 1];
            const bool odd = (h & 1);
            fv[2 * p]     = odd ? make_float2(q.z, q.w) : make_float2(q.x, q.y);
            fv[2 * p + 1] = odd ? make_float2(q.x, q.y) : make_float2(q.z, q.w);
        }
    } else {
        #pragma unroll
        for (int p = 0; p < 8; ++p) {
            const unsigned hA = ((unsigned)bi[0]       ^ hrest[p]) & TMASK;
            const unsigned hB = ((unsigned)(bi[0] + 1) ^ hrest[p]) & TMASK;
            fv[2 * p]     = tl[hA];
            fv[2 * p + 1] = tl[hB];
        }
    }

    float wt[16];
    #pragma unroll
    for (int c = 0; c < 16; ++c) {
        float w = ( c       & 1) ? fr[0] : om[0];
        w      *= ((c >> 1) & 1) ? fr[1] : om[1];
        w      *= ((c >> 2) & 1) ? fr[2] : om[2];
        w      *= ((c >> 3) & 1) ? fr[3] : om[3];
        wt[c] = w;
    }

    float a0 = 0.0f, a1 = 0.0f;
    #pragma unroll
    for (int c = 0; c < 16; ++c) {
        a0 = fmaf(wt[c], fv[c].x, a0);
        a1 = fmaf(wt[c], fv[c].y, a1);
    }
    featbf[(size_t)l * N + n] = (unsigned)f2bf(a0) | ((unsigned)f2bf(a1) << 16);
}

__global__ __launch_bounds__(256, 4)
void ingp_encode_f32(const float4* __restrict__ x,
                     const float2* __restrict__ table,
                     unsigned*     __restrict__ featbf,
                     int N, int chunksPerLevel, ResArr res)
{
    const int l     = blockIdx.x / chunksPerLevel;
    const int chunk = blockIdx.x - l * chunksPerLevel;
    encode_point_f32(x, table, featbf, N, l, chunk * 256 + (int)threadIdx.x, res);
}

// ---------------------------------------------------------------------------
// MFMA MLP — r6-verified: all weight frags staged through block-shared LDS,
// tilesPerWave=16 (1024 blocks, one full round at 4 blocks/CU). UNCHANGED.
// ---------------------------------------------------------------------------
#define TILE_BODY(P0, A0)                                                     \
{                                                                             \
    asm volatile("" : "+v"(idx0));   /* block LICM of the wlds reads below */ \
    float4v acc0[4];                                                          \
    _Pragma("unroll")                                                         \
    for (int t = 0; t < 4; ++t) {                                             \
        acc0[t] = (float4v){0.f, 0.f, 0.f, 0.f};                              \
        acc0[t] = __builtin_amdgcn_mfma_f32_16x16x32_bf16(A0, w0f[t], acc0[t], 0, 0, 0); \
    }                                                                         \
    _Pragma("unroll")                                                         \
    for (int t = 0; t < 4; ++t)                                               \
        _Pragma("unroll")                                                     \
        for (int r = 0; r < 4; ++r)                                           \
            *(unsigned short*)(hbase + (q * 4 + r) * 144 + (t * 16 + nn) * 2) = \
                f2bf(fmaxf(acc0[t][r], 0.0f));                                \
    short8 a1[2];                                                             \
    _Pragma("unroll")                                                         \
    for (int s = 0; s < 2; ++s)                                               \
        a1[s] = *(const short8*)(hbase + nn * 144 + s * 64 + q * 16);         \
    float4v acc1[4];                                                          \
    _Pragma("unroll")                                                         \
    for (int t = 0; t < 4; ++t) {                                             \
        acc1[t] = (float4v){0.f, 0.f, 0.f, 0.f};                              \
        _Pragma("unroll")                                                     \
        for (int s = 0; s < 2; ++s)                                           \
            acc1[t] = __builtin_amdgcn_mfma_f32_16x16x32_bf16(a1[s], w1f[s][t], acc1[t], 0, 0, 0); \
    }                                                                         \
    _Pragma("unroll")                                                         \
    for (int t = 0; t < 4; ++t)                                               \
        _Pragma("unroll")                                                     \
        for (int r = 0; r < 4; ++r)                                           \
            *(unsigned short*)(hbase + (q * 4 + r) * 144 + (t * 16 + nn) * 2) = \
                f2bf(fmaxf(acc1[t][r], 0.0f));                                \
    short8 a2[2];                                                             \
    _Pragma("unroll")                                                         \
    for (int s = 0; s < 2; ++s)                                               \
        a2[s] = *(const short8*)(hbase + nn * 144 + s * 64 + q * 16);         \
    float4v acc2[4];                                                          \
    _Pragma("unroll")                                                         \
    for (int t = 0; t < 4; ++t) {                                             \
        acc2[t] = (float4v){0.f, 0.f, 0.f, 0.f};                              \
        _Pragma("unroll")                                                     \
        for (int s = 0; s < 2; ++s) {                                         \
            const short8 w2x = *(const short8*)(wlds + ((12 + s * 4 + t) * 64 + lane) * 16 + idx0); \
            acc2[t] = __builtin_amdgcn_mfma_f32_16x16x32_bf16(a2[s], w2x, acc2[t], 0, 0, 0); \
        }                                                                     \
    }                                                                         \
    _Pragma("unroll")                                                         \
    for (int t = 0; t < 4; ++t)                                               \
        _Pragma("unroll")                                                     \
        for (int r = 0; r < 4; ++r)                                           \
            *(unsigned short*)(hbase + (q * 4 + r) * 144 + (t * 16 + nn) * 2) = \
                f2bf(fmaxf(acc2[t][r], 0.0f));                                \
    short8 a3[2];                                                             \
    _Pragma("unroll")                                                         \
    for (int s = 0; s < 2; ++s)                                               \
        a3[s] = *(const short8*)(hbase + nn * 144 + s * 64 + q * 16);         \
    float4v oc = (float4v){0.f, 0.f, 0.f, 0.f};                               \
    _Pragma("unroll")                                                         \
    for (int s = 0; s < 2; ++s) {                                             \
        const short8 wox = *(const short8*)(wlds + ((20 + s) * 64 + lane) * 16 + idx0); \
        oc = __builtin_amdgcn_mfma_f32_16x16x32_bf16(a3[s], wox, oc, 0, 0, 0); \
    }                                                                         \
    if (nn < 3) {                                                             \
        _Pragma("unroll")                                                     \
        for (int r = 0; r < 4; ++r) {                                         \
            const int pt = (P0) + q * 4 + r;                                  \
            if (pt < N) out[pt * 3 + nn] = oc[r] + bias;                      \
        }                                                                     \
    }                                                                         \
}

static __device__ __forceinline__
void stage_wlds(const float* __restrict__ w0, const float* __restrict__ w1,
                const float* __restrict__ w2, const float* __restrict__ wout,
                char* wlds, int tid)
{
    if (tid < 64) {
        const int lane = tid;
        const int q  = lane >> 4;
        const int nn = lane & 15;
        #pragma unroll
        for (int t = 0; t < 4; ++t) {
            const float* wr = w0 + (t * 16 + nn) * 32 + q * 8;
            short8 f;
            #pragma unroll
            for (int e = 0; e < 8; ++e) f[e] = (short)f2bf(wr[e]);
            *(short8*)(wlds + ((0 + t) * 64 + lane) * 16) = f;
        }
        #pragma unroll
        for (int s = 0; s < 2; ++s)
            #pragma unroll
            for (int t = 0; t < 4; ++t) {
                const float* wr1 = w1 + (t * 16 + nn) * 64 + s * 32 + q * 8;
                const float* wr2 = w2 + (t * 16 + nn) * 64 + s * 32 + q * 8;
                short8 f1, f2;
                #pragma unroll
                for (int e = 0; e < 8; ++e) {
                    f1[e] = (short)f2bf(wr1[e]);
                    f2[e] = (short)f2bf(wr2[e]);
                }
                *(short8*)(wlds + (( 4 + s * 4 + t) * 64 + lane) * 16) = f1;
                *(short8*)(wlds + ((12 + s * 4 + t) * 64 + lane) * 16) = f2;
            }
        #pragma unroll
        for (int s = 0; s < 2; ++s) {
            short8 f;
            #pragma unroll
            for (int e = 0; e < 8; ++e)
                f[e] = (nn < 3) ? (short)f2bf(wout[nn * 64 + s * 32 + q * 8 + e])
                                : (short)0;
            *(short8*)(wlds + ((20 + s) * 64 + lane) * 16) = f;
        }
    }
}

template <int NT>
static __device__ __forceinline__
void mlp_run(const unsigned* __restrict__ featbf,  // [NLVL][N]
             const float*    __restrict__ bout,
             float*          __restrict__ out,
             const char* wlds, char* hbase,
             int N, int firstTile, int lane)
{
    const int q  = lane >> 4;
    const int nn = lane & 15;

    short8 w0f[4];
    #pragma unroll
    for (int t = 0; t < 4; ++t)
        w0f[t] = *(const short8*)(wlds + ((0 + t) * 64 + lane) * 16);
    short8 w1f[2][4];
    #pragma unroll
    for (int s = 0; s < 2; ++s)
        #pragma unroll
        for (int t = 0; t < 4; ++t)
            w1f[s][t] = *(const short8*)(wlds + ((4 + s * 4 + t) * 64 + lane) * 16);
    const float bias = (nn < 3) ? bout[nn] : 0.0f;

    int idx0 = 0;   // always 0; laundered per tile (see TILE_BODY)

    unsigned ufA[4], ufB[4];
    {
        const int pA = (firstTile * 16 < N) ? (firstTile * 16 + nn) : 0;
        const int pB = ((firstTile + 1) * 16 < N) ? ((firstTile + 1) * 16 + nn) : 0;
        #pragma unroll
        for (int v = 0; v < 4; ++v) {
            ufA[v] = featbf[(size_t)(q * 4 + v) * N + pA];
            ufB[v] = featbf[(size_t)(q * 4 + v) * N + pB];
        }
    }

    for (int it = 0; it < NT; it += 2) {
        const int p0A = (firstTile + it) * 16;
        if (p0A >= N) break;

        short8 a0A;
        #pragma unroll
        for (int v = 0; v < 4; ++v) {
            a0A[2 * v]     = (short)(ufA[v] & 0xffffu);
            a0A[2 * v + 1] = (short)(ufA[v] >> 16);
        }
        {
            const int p0n = (firstTile + it + 2) * 16;
            const bool more = (it + 2 < NT) && (p0n < N);
            const int pn = more ? (p0n + nn) : 0;
            #pragma unroll
            for (int v = 0; v < 4; ++v)
                ufA[v] = featbf[(size_t)(q * 4 + v) * N + pn];
        }
        TILE_BODY(p0A, a0A)

        const int p0B = (firstTile + it + 1) * 16;
        if (p0B < N && it + 1 < NT) {
            short8 a0B;
            #pragma unroll
            for (int v = 0; v < 4; ++v) {
                a0B[2 * v]     = (short)(ufB[v] & 0xffffu);
                a0B[2 * v + 1] = (short)(ufB[v] >> 16);
            }
            {
                const int p0n = (firstTile + it + 3) * 16;
                const bool more = (it + 3 < NT) && (p0n < N);
                const int pn = more ? (p0n + nn) : 0;
                #pragma unroll
                for (int v = 0; v < 4; ++v)
                    ufB[v] = featbf[(size_t)(q * 4 + v) * N + pn];
            }
            TILE_BODY(p0B, a0B)
        }
    }
}

#define TILES_PER_WAVE 16

__global__ __launch_bounds__(256, 4)
void ingp_mlp_mfma(const unsigned* __restrict__ featbf,
                   const float*    __restrict__ w0,
                   const float*    __restrict__ w1,
                   const float*    __restrict__ w2,
                   const float*    __restrict__ wout,
                   const float*    __restrict__ bout,
                   float*          __restrict__ out,
                   int N)
{
    __shared__ char lds_raw[4 * 16 * 144];   // per-wave hidden staging (9216 B)
    __shared__ char wlds[22 * 64 * 16];      // all weight frags (22528 B)

    const int tid = (int)threadIdx.x;
    stage_wlds(w0, w1, w2, wout, wlds, tid);
    __syncthreads();

    const int wave = tid >> 6;
    const int lane = tid & 63;
    char* hbase = lds_raw + wave * (16 * 144);
    mlp_run<TILES_PER_WAVE>(featbf, bout, out, wlds, hbase, N,
                            ((int)blockIdx.x * 4 + wave) * TILES_PER_WAVE, lane);
}

// ---------------------------------------------------------------------------
// Fallback: fused scalar kernel (used only if ws is too small for features).
// ---------------------------------------------------------------------------
__global__ __launch_bounds__(256, 2)
void ingp_fused(const float4* __restrict__ x,
                const float2* __restrict__ table,
                const float*  __restrict__ w0,
                const float*  __restrict__ w1,
                const float*  __restrict__ w2,
                const float*  __restrict__ wout,
                const float*  __restrict__ bout,
                float*        __restrict__ out,
                int N, ResArr res)
{
    const int n = blockIdx.x * blockDim.x + threadIdx.x;
    if (n >= N) return;

    const float4 xv = x[n];
    const float px[4] = {xv.x, xv.y, xv.z, xv.w};

    float h1[64];
    #pragma unroll
    for (int j = 0; j < 64; ++j) h1[j] = 0.0f;

    float a0p = 0.0f, a1p = 0.0f;

    #pragma unroll 1
    for (int l = 0; l < NLVL; ++l) {
        int   rm[4], bi[4];
        float fr[4], om[4];
        #pragma unroll
        for (int d = 0; d < 4; ++d) {
            const int r = res.m1[l * 4 + d];
            rm[d] = r;
            const float pos = px[d] * (float)r;
            const float fb  = floorf(pos);
            fr[d] = pos - fb;
            om[d] = 1.0f - fr[d];
            bi[d] = (int)fb;
        }
        const float2* tl = table + (size_t)l * TSZ;

        float2 fv[16];
        float  wt[16];
        #pragma unroll
        for (int c = 0; c < 16; ++c) {
            int c0 = bi[0] + ( c       & 1);
            int c1 = bi[1] + ((c >> 1) & 1);
            int c2 = bi[2] + ((c >> 2) & 1);
            int c3 = bi[3] + ((c >> 3) & 1);
            c0 = min(max(c0, 0), rm[0]);
            c1 = min(max(c1, 0), rm[1]);
            c2 = min(max(c2, 0), rm[2]);
            c3 = min(max(c3, 0), rm[3]);
            const unsigned hh = (unsigned)c0
                              ^ ((unsigned)c1 * 2654435761u)
                              ^ ((unsigned)c2 * 805459861u)
                              ^ ((unsigned)c3 * 3674653429u);
            fv[c] = tl[hh & TMASK];
            float w = ( c       & 1) ? fr[0] : om[0];
            w      *= ((c >> 1) & 1) ? fr[1] : om[1];
            w      *= ((c >> 2) & 1) ? fr[2] : om[2];
            w      *= ((c >> 3) & 1) ? fr[3] : om[3];
            wt[c] = w;
        }
        {
            const int lp = (l == 0) ? 0 : (l - 1);
            const float* w0c = w0 + 2 * lp;
            #pragma unroll
            for (int j = 0; j < 64; ++j)
                h1[j] = fmaf(w0c[j * 32], a0p, fmaf(w0c[j * 32 + 1], a1p, h1[j]));
        }
        float a0 = 0.0f, a1 = 0.0f;
        #pragma unroll
        for (int c = 0; c < 16; ++c) {
            a0 = fmaf(wt[c], fv[c].x, a0);
            a1 = fmaf(wt[c], fv[c].y, a1);
        }
        a0p = a0; a1p = a1;
    }
    {
        const float* w0c = w0 + 2 * (NLVL - 1);
        #pragma unroll
        for (int j = 0; j < 64; ++j)
            h1[j] = fmaf(w0c[j * 32], a0p, fmaf(w0c[j * 32 + 1], a1p, h1[j]));
    }
    #pragma unroll
    for (int j = 0; j < 64; ++j) h1[j] = fmaxf(h1[j], 0.0f);

    float h2[64];
    #pragma unroll
    for (int j = 0; j < 64; ++j) {
        float acc = 0.0f;
        const float* wr = w1 + j * 64;
        #pragma unroll
        for (int i = 0; i < 64; ++i) acc = fmaf(wr[i], h1[i], acc);
        h2[j] = fmaxf(acc, 0.0f);
    }
    float h3[64];
    #pragma unroll
    for (int j = 0; j < 64; ++j) {
        float acc = 0.0f;
        const float* wr = w2 + j * 64;
        #pragma unroll
        for (int i = 0; i < 64; ++i) acc = fmaf(wr[i], h2[i], acc);
        h3[j] = fmaxf(acc, 0.0f);
    }
    float o[3];
    #pragma unroll
    for (int k = 0; k < 3; ++k) {
        float acc = bout[k];
        const float* wr = wout + k * 64;
        #pragma unroll
        for (int i = 0; i < 64; ++i) acc = fmaf(wr[i], h3[i], acc);
        o[k] = acc;
    }
    out[n * 3 + 0] = o[0];
    out[n * 3 + 1] = o[1];
    out[n * 3 + 2] = o[2];
}

extern "C" void kernel_launch(void* const* d_in, const int* in_sizes, int n_in,
                              void* d_out, int out_size, void* d_ws, size_t ws_size,
                              hipStream_t stream) {
    (void)n_in; (void)out_size;

    const float* x     = (const float*)d_in[0];
    const float* table = (const float*)d_in[1];
    const float* w0    = (const float*)d_in[2];
    const float* w1    = (const float*)d_in[3];
    const float* w2    = (const float*)d_in[4];
    const float* wout  = (const float*)d_in[5];
    const float* bout  = (const float*)d_in[6];
    float* out = (float*)d_out;

    const int N = in_sizes[0] / 4;

    // Replicate numpy's float64 resolution computation bit-for-bit (same
    // glibc pow). Levels 5/10/15 of dim 3 sit on exact integer boundaries
    // (8^(5/15)==2), so floor() must see the same double as numpy produced.
    ResArr res;
    for (int d = 0; d < 4; ++d) {
        const double minr = 16.0;
        const double maxr = (d == 3) ? 128.0 : 256.0;
        const double growth = pow(maxr / minr, 1.0 / (double)(NLVL - 1));
        for (int l = 0; l < NLVL; ++l) {
            const int r = (int)floor(minr * pow(growth, (double)l));
            res.m1[l * 4 + d] = r - 1;
        }
    }

    const size_t tblBytes  = (size_t)NLVL * TSZ * sizeof(unsigned);      // 32 MiB
    const size_t featBytes = (size_t)NLVL * (size_t)N * sizeof(unsigned);
    const int chunksPerLevel = (N + 255) / 256;
    const int totalUnits     = NLVL * chunksPerLevel;

    const int tiles  = (N + 15) / 16;
    const int waves  = (tiles + TILES_PER_WAVE - 1) / TILES_PER_WAVE;
    const int blocks = (waves + 3) / 4;

    // Probe cooperative-launch support + co-residency capacity once.
    static int s_coopGrid = -2;   // -2 = unprobed, 0 = unsupported, >0 = grid
    if (s_coopGrid == -2) {
        s_coopGrid = 0;
        hipDeviceProp_t prop;
        if (hipGetDeviceProperties(&prop, 0) == hipSuccess && prop.cooperativeLaunch) {
            int maxB = 0;
            if (hipOccupancyMaxActiveBlocksPerMultiprocessor(
                    &maxB, (const void*)ingp_cvt_encode, 256, 0) == hipSuccess &&
                maxB > 0) {
                long long cap = (long long)maxB * prop.multiProcessorCount;
                if (cap > 2048) cap = 2048;
                s_coopGrid = (int)cap;
            }
        }
    }

    if (ws_size >= tblBytes + featBytes) {
        unsigned* tblbf  = (unsigned*)d_ws;
        unsigned* featbf = (unsigned*)((char*)d_ws + tblBytes);

        bool launched = false;
        if (s_coopGrid > 0) {
            const float4* x4 = (const float4*)x;
            const float4* t4 = (const float4*)table;
            int N_ = N, cpl_ = chunksPerLevel, tu_ = totalUnits;
            void* args[] = { (void*)&x4, (void*)&t4, (void*)&tblbf, (void*)&featbf,
                             (void*)&N_, (void*)&cpl_, (void*)&tu_, (void*)&res };
            hipError_t err = hipLaunchCooperativeKernel(
                (const void*)ingp_cvt_encode, dim3(s_coopGrid), dim3(256),
                args, 0, stream);
            if (err == hipSuccess) {
                launched = true;
            } else {
                s_coopGrid = 0;   // don't retry on later calls
            }
        }
        if (!launched) {
            hipLaunchKernelGGL(cvt_table, dim3(2048), dim3(256), 0, stream,
                               (const float4*)table, (uint2*)tblbf,
                               (int)(NLVL * TSZ / 2));
            hipLaunchKernelGGL(ingp_encode_bf16, dim3(totalUnits), dim3(256),
                               0, stream, (const float4*)x, tblbf,
                               featbf, N, chunksPerLevel, res);
        }

        hipLaunchKernelGGL(ingp_mlp_mfma, dim3(blocks), dim3(256), 0, stream,
                           featbf, w0, w1, w2, wout, bout, out, N);
    } else if (ws_size >= featBytes) {
        unsigned* featbf = (unsigned*)d_ws;
        hipLaunchKernelGGL(ingp_encode_f32, dim3(totalUnits), dim3(256),
                           0, stream, (const float4*)x, (const float2*)table,
                           featbf, N, chunksPerLevel, res);

        hipLaunchKernelGGL(ingp_mlp_mfma, dim3(blocks), dim3(256), 0, stream,
                           featbf, w0, w1, w2, wout, bout, out, N);
    } else {
        hipLaunchKernelGGL(ingp_fused, dim3((N + 255) / 256), dim3(256), 0, stream,
                           (const float4*)x, (const float2*)table,
                           w0, w1, w2, wout, bout, out, N, res);
    }
}

// Round 8
// 1134.744 us; speedup vs baseline: 1.0166x; 1.0166x over previous
//
#include <hip/hip_runtime.h>
#include <hip/hip_cooperative_groups.h>
#include <math.h>

namespace cg = cooperative_groups;

#define NLVL  16
#define TSZ   (1u << 19)
#define TMASK (TSZ - 1u)

struct ResArr { int m1[NLVL * 4]; };  // per level, per dim: res-1

typedef short  short8  __attribute__((ext_vector_type(8)));
typedef float  float4v __attribute__((ext_vector_type(4)));

static __device__ __forceinline__ unsigned short f2bf(float f) {
    unsigned u = __float_as_uint(f);
    return (unsigned short)((u + 0x7fffu + ((u >> 16) & 1u)) >> 16);  // RNE
}

// ---------------------------------------------------------------------------
// Encode body, bf16-table version (verified r2-r6: ~96% of the L2
// request-service roofline at ~10 req/point-level).
// ---------------------------------------------------------------------------
static __device__ __forceinline__
void encode_point_bf16(const float4*   __restrict__ x,
                       const unsigned* __restrict__ tbl,     // [NLVL][TSZ] bf16 pairs
                       unsigned*       __restrict__ featbf,  // [NLVL][N] bf16 pairs
                       int N, int l, int n, const ResArr& res)
{
    if (n < N) {
        const float4 xv = x[n];
        const float px[4] = {xv.x, xv.y, xv.z, xv.w};

        int   bi[4];
        float fr[4], om[4];
        #pragma unroll
        for (int d = 0; d < 4; ++d) {
            const int r = res.m1[l * 4 + d];       // wave-uniform -> scalar
            const float pos = px[d] * (float)r;
            const float fb  = floorf(pos);
            fr[d] = pos - fb;
            om[d] = 1.0f - fr[d];
            bi[d] = (int)fb;
        }
        const unsigned* tl  = tbl + (size_t)l * TSZ;
        const uint2*    tl2 = (const uint2*)tl;
        const uint4*    tl4 = (const uint4*)tl;

        unsigned hrest[8];
        #pragma unroll
        for (int p = 0; p < 8; ++p) {
            const int c1 = bi[1] + ( p       & 1);
            const int c2 = bi[2] + ((p >> 1) & 1);
            const int c3 = bi[3] + ((p >> 2) & 1);
            hrest[p] = ((unsigned)c1 * 2654435761u)
                     ^ ((unsigned)c2 * 805459861u)
                     ^ ((unsigned)c3 * 3674653429u);
        }

        const int b0 = bi[0];
        unsigned ea[8], eb[8];   // packed bf16 pairs: dim0-offset 0 / offset 1

        if ((b0 & 1) == 0) {
            // bi0 even: partner index = h ^ 1 -> one aligned 8B load per pair
            #pragma unroll
            for (int p = 0; p < 8; ++p) {
                const unsigned h = ((unsigned)b0 ^ hrest[p]) & TMASK;
                const uint2 q = tl2[h >> 1];
                ea[p] = (h & 1u) ? q.y : q.x;
                eb[p] = (h & 1u) ? q.x : q.y;
            }
        } else if ((b0 & 3) == 1) {
            // bi0 % 4 == 1: partner = h ^ 3 -> same aligned 16B group
            #pragma unroll
            for (int p = 0; p < 8; ++p) {
                const unsigned hA = ((unsigned)b0 ^ hrest[p]) & TMASK;
                const uint4 q = tl4[hA >> 2];
                const unsigned jA  = hA & 3u;
                const unsigned loA = (jA & 2u) ? q.z : q.x;
                const unsigned hiA = (jA & 2u) ? q.w : q.y;
                const unsigned loB = (jA & 2u) ? q.x : q.z;
                const unsigned hiB = (jA & 2u) ? q.y : q.w;
                ea[p] = (jA & 1u) ? hiA : loA;
                eb[p] = (jA & 1u) ? loB : hiB;
            }
        } else {
            // bi0 % 4 == 3: partner differs in >= 3 low bits -> two 4B loads
            #pragma unroll
            for (int p = 0; p < 8; ++p) {
                const unsigned hA = ((unsigned)b0       ^ hrest[p]) & TMASK;
                const unsigned hB = ((unsigned)(b0 + 1) ^ hrest[p]) & TMASK;
                ea[p] = tl[hA];
                eb[p] = tl[hB];
            }
        }

        float2 fv[16];   // fv[2p] = dim0-offset 0, fv[2p+1] = dim0-offset 1
        #pragma unroll
        for (int p = 0; p < 8; ++p) {
            fv[2 * p]     = make_float2(__uint_as_float(ea[p] << 16),
                                        __uint_as_float(ea[p] & 0xffff0000u));
            fv[2 * p + 1] = make_float2(__uint_as_float(eb[p] << 16),
                                        __uint_as_float(eb[p] & 0xffff0000u));
        }

        float wt[16];
        #pragma unroll
        for (int c = 0; c < 16; ++c) {
            float w = ( c       & 1) ? fr[0] : om[0];
            w      *= ((c >> 1) & 1) ? fr[1] : om[1];
            w      *= ((c >> 2) & 1) ? fr[2] : om[2];
            w      *= ((c >> 3) & 1) ? fr[3] : om[3];
            wt[c] = w;
        }

        float a0 = 0.0f, a1 = 0.0f;
        #pragma unroll
        for (int c = 0; c < 16; ++c) {       // same order as reference einsum
            a0 = fmaf(wt[c], fv[c].x, a0);
            a1 = fmaf(wt[c], fv[c].y, a1);
        }
        featbf[(size_t)l * N + n] = (unsigned)f2bf(a0) | ((unsigned)f2bf(a1) << 16);
    }
}

// ---------------------------------------------------------------------------
// COOPERATIVE cvt+encode, round 8: ATOMIC WORK QUEUE ordering. r7's
// grid-stride drifted out of lockstep -> concurrent window spanned >=3
// levels -> per-XCD L2 table replica (4MB cap) thrashed -> FETCH 234MB ->
// 3.2GB. Fix: blocks PULL the next unit index from a global counter, so
// assignment order is strictly sequential (emulates the HW dispatcher's
// in-order sliding window). Window = in-flight (<=2048) + reserved next
// (<=2048) <= 4096 units <= 2 levels <= 4MB replica. The grab for unit k+1
// is issued BEFORE processing unit k (latency hidden under gathers).
// Atomic rate ~120/us on one line (~20-40% of one L2 channel's atomic
// service) - safe. Keeps the wins: no cvt dispatch+gap, no 65536-block
// launch/drain churn.
// ---------------------------------------------------------------------------
__global__ __launch_bounds__(256, 8)
void ingp_cvt_encode(const float4*   __restrict__ x,
                     const float4*   __restrict__ table4,   // f32 table as float4
                     unsigned*       __restrict__ tblbf,
                     unsigned*       __restrict__ featbf,
                     unsigned*       __restrict__ qcounter,
                     int N, int chunksPerLevel, int totalUnits, ResArr res)
{
    const int tid = (int)threadIdx.x;
    const int gsz = (int)gridDim.x * 256;

    // ---- phase 1: f32 pairs -> packed bf16 pairs; init the work counter ----
    {
        uint2* o = (uint2*)tblbf;
        const int totalPairs = (int)(NLVL * TSZ / 2);
        for (int i = (int)blockIdx.x * 256 + tid; i < totalPairs; i += gsz) {
            const float4 e = table4[i];
            o[i] = make_uint2((unsigned)f2bf(e.x) | ((unsigned)f2bf(e.y) << 16),
                              (unsigned)f2bf(e.z) | ((unsigned)f2bf(e.w) << 16));
        }
        if (blockIdx.x == 0 && tid == 0) *qcounter = (unsigned)gridDim.x;
    }
    __threadfence();
    cg::this_grid().sync();

    // ---- phase 2: encode; in-order unit assignment via atomic pull ----
    __shared__ unsigned sNext;
    int u = (int)blockIdx.x;          // first gridDim units are pre-assigned
    while (u < totalUnits) {
        if (tid == 0) sNext = atomicAdd(qcounter, 1u);   // reserve next early
        const int l     = u / chunksPerLevel;
        const int chunk = u - l * chunksPerLevel;
        encode_point_bf16(x, tblbf, featbf, N, l, chunk * 256 + tid, res);
        __syncthreads();              // sNext visible to all lanes
        u = (int)sNext;
        __syncthreads();              // all read sNext before next overwrite
    }
}

// ---------------------------------------------------------------------------
// Non-cooperative fallbacks (r6-verified path).
// ---------------------------------------------------------------------------
__global__ __launch_bounds__(256)
void cvt_table(const float4* __restrict__ t, uint2* __restrict__ o, int totalPairs)
{
    for (int i = blockIdx.x * 256 + (int)threadIdx.x; i < totalPairs;
         i += gridDim.x * 256) {
        const float4 e = t[i];
        o[i] = make_uint2((unsigned)f2bf(e.x) | ((unsigned)f2bf(e.y) << 16),
                          (unsigned)f2bf(e.z) | ((unsigned)f2bf(e.w) << 16));
    }
}

__global__ __launch_bounds__(256, 4)
void ingp_encode_bf16(const float4*   __restrict__ x,
                      const unsigned* __restrict__ tbl,
                      unsigned*       __restrict__ featbf,
                      int N, int chunksPerLevel, ResArr res)
{
    const int l     = blockIdx.x / chunksPerLevel;
    const int chunk = blockIdx.x - l * chunksPerLevel;
    encode_point_bf16(x, tbl, featbf, N, l, chunk * 256 + (int)threadIdx.x, res);
}

// f32-table encode (fallback when ws can't hold the bf16 table copy).
static __device__ __forceinline__
void encode_point_f32(const float4* __restrict__ x,
                      const float2* __restrict__ table,
                      unsigned*     __restrict__ featbf,
                      int N, int l, int n, const ResArr& res)
{
    if (n >= N) return;

    const float4 xv = x[n];
    const float px[4] = {xv.x, xv.y, xv.z, xv.w};

    int   bi[4];
    float fr[4], om[4];
    #pragma unroll
    for (int d = 0; d < 4; ++d) {
        const int r = res.m1[l * 4 + d];
        const float pos = px[d] * (float)r;
        const float fb  = floorf(pos);
        fr[d] = pos - fb;
        om[d] = 1.0f - fr[d];
        bi[d] = (int)fb;
    }
    const float2* tl  = table + (size_t)l * TSZ;
    const float4* tl4 = (const float4*)tl;

    unsigned hrest[8];
    #pragma unroll
    for (int p = 0; p < 8; ++p) {
        const int c1 = bi[1] + ( p       & 1);
        const int c2 = bi[2] + ((p >> 1) & 1);
        const int c3 = bi[3] + ((p >> 2) & 1);
        hrest[p] = ((unsigned)c1 * 2654435761u)
                 ^ ((unsigned)c2 * 805459861u)
                 ^ ((unsigned)c3 * 3674653429u);
    }

    float2 fv[16];
    if ((bi[0] & 1) == 0) {
        #pragma unroll
        for (int p = 0; p < 8; ++p) {
            const unsigned h = ((unsigned)bi[0] ^ hrest[p]) & TMASK;
            const float4 q = tl4[h >> 1];
            const bool odd = (h & 1);
            fv[2 * p]     = odd ? make_float2(q.z, q.w) : make_float2(q.x, q.y);
            fv[2 * p + 1] = odd ? make_float2(q.x, q.y) : make_float2(q.z, q.w);
        }
    } else {
        #pragma unroll
        for (int p = 0; p < 8; ++p) {
            const unsigned hA = ((unsigned)bi[0]       ^ hrest[p]) & TMASK;
            const unsigned hB = ((unsigned)(bi[0] + 1) ^ hrest[p]) & TMASK;
            fv[2 * p]     = tl[hA];
            fv[2 * p + 1] = tl[hB];
        }
    }

    float wt[16];
    #pragma unroll
    for (int c = 0; c < 16; ++c) {
        float w = ( c       & 1) ? fr[0] : om[0];
        w      *= ((c >> 1) & 1) ? fr[1] : om[1];
        w      *= ((c >> 2) & 1) ? fr[2] : om[2];
        w      *= ((c >> 3) & 1) ? fr[3] : om[3];
        wt[c] = w;
    }

    float a0 = 0.0f, a1 = 0.0f;
    #pragma unroll
    for (int c = 0; c < 16; ++c) {
        a0 = fmaf(wt[c], fv[c].x, a0);
        a1 = fmaf(wt[c], fv[c].y, a1);
    }
    featbf[(size_t)l * N + n] = (unsigned)f2bf(a0) | ((unsigned)f2bf(a1) << 16);
}

__global__ __launch_bounds__(256, 4)
void ingp_encode_f32(const float4* __restrict__ x,
                     const float2* __restrict__ table,
                     unsigned*     __restrict__ featbf,
                     int N, int chunksPerLevel, ResArr res)
{
    const int l     = blockIdx.x / chunksPerLevel;
    const int chunk = blockIdx.x - l * chunksPerLevel;
    encode_point_f32(x, table, featbf, N, l, chunk * 256 + (int)threadIdx.x, res);
}

// ---------------------------------------------------------------------------
// MFMA MLP — r6-verified: all weight frags staged through block-shared LDS,
// tilesPerWave=16 (1024 blocks, one full round at 4 blocks/CU). UNCHANGED.
// ---------------------------------------------------------------------------
#define TILE_BODY(P0, A0)                                                     \
{                                                                             \
    asm volatile("" : "+v"(idx0));   /* block LICM of the wlds reads below */ \
    float4v acc0[4];                                                          \
    _Pragma("unroll")                                                         \
    for (int t = 0; t < 4; ++t) {                                             \
        acc0[t] = (float4v){0.f, 0.f, 0.f, 0.f};                              \
        acc0[t] = __builtin_amdgcn_mfma_f32_16x16x32_bf16(A0, w0f[t], acc0[t], 0, 0, 0); \
    }                                                                         \
    _Pragma("unroll")                                                         \
    for (int t = 0; t < 4; ++t)                                               \
        _Pragma("unroll")                                                     \
        for (int r = 0; r < 4; ++r)                                           \
            *(unsigned short*)(hbase + (q * 4 + r) * 144 + (t * 16 + nn) * 2) = \
                f2bf(fmaxf(acc0[t][r], 0.0f));                                \
    short8 a1[2];                                                             \
    _Pragma("unroll")                                                         \
    for (int s = 0; s < 2; ++s)                                               \
        a1[s] = *(const short8*)(hbase + nn * 144 + s * 64 + q * 16);         \
    float4v acc1[4];                                                          \
    _Pragma("unroll")                                                         \
    for (int t = 0; t < 4; ++t) {                                             \
        acc1[t] = (float4v){0.f, 0.f, 0.f, 0.f};                              \
        _Pragma("unroll")                                                     \
        for (int s = 0; s < 2; ++s)                                           \
            acc1[t] = __builtin_amdgcn_mfma_f32_16x16x32_bf16(a1[s], w1f[s][t], acc1[t], 0, 0, 0); \
    }                                                                         \
    _Pragma("unroll")                                                         \
    for (int t = 0; t < 4; ++t)                                               \
        _Pragma("unroll")                                                     \
        for (int r = 0; r < 4; ++r)                                           \
            *(unsigned short*)(hbase + (q * 4 + r) * 144 + (t * 16 + nn) * 2) = \
                f2bf(fmaxf(acc1[t][r], 0.0f));                                \
    short8 a2[2];                                                             \
    _Pragma("unroll")                                                         \
    for (int s = 0; s < 2; ++s)                                               \
        a2[s] = *(const short8*)(hbase + nn * 144 + s * 64 + q * 16);         \
    float4v acc2[4];                                                          \
    _Pragma("unroll")                                                         \
    for (int t = 0; t < 4; ++t) {                                             \
        acc2[t] = (float4v){0.f, 0.f, 0.f, 0.f};                              \
        _Pragma("unroll")                                                     \
        for (int s = 0; s < 2; ++s) {                                         \
            const short8 w2x = *(const short8*)(wlds + ((12 + s * 4 + t) * 64 + lane) * 16 + idx0); \
            acc2[t] = __builtin_amdgcn_mfma_f32_16x16x32_bf16(a2[s], w2x, acc2[t], 0, 0, 0); \
        }                                                                     \
    }                                                                         \
    _Pragma("unroll")                                                         \
    for (int t = 0; t < 4; ++t)                                               \
        _Pragma("unroll")                                                     \
        for (int r = 0; r < 4; ++r)                                           \
            *(unsigned short*)(hbase + (q * 4 + r) * 144 + (t * 16 + nn) * 2) = \
                f2bf(fmaxf(acc2[t][r], 0.0f));                                \
    short8 a3[2];                                                             \
    _Pragma("unroll")                                                         \
    for (int s = 0; s < 2; ++s)                                               \
        a3[s] = *(const short8*)(hbase + nn * 144 + s * 64 + q * 16);         \
    float4v oc = (float4v){0.f, 0.f, 0.f, 0.f};                               \
    _Pragma("unroll")                                                         \
    for (int s = 0; s < 2; ++s) {                                             \
        const short8 wox = *(const short8*)(wlds + ((20 + s) * 64 + lane) * 16 + idx0); \
        oc = __builtin_amdgcn_mfma_f32_16x16x32_bf16(a3[s], wox, oc, 0, 0, 0); \
    }                                                                         \
    if (nn < 3) {                                                             \
        _Pragma("unroll")                                                     \
        for (int r = 0; r < 4; ++r) {                                         \
            const int pt = (P0) + q * 4 + r;                                  \
            if (pt < N) out[pt * 3 + nn] = oc[r] + bias;                      \
        }                                                                     \
    }                                                                         \
}

static __device__ __forceinline__
void stage_wlds(const float* __restrict__ w0, const float* __restrict__ w1,
                const float* __restrict__ w2, const float* __restrict__ wout,
                char* wlds, int tid)
{
    if (tid < 64) {
        const int lane = tid;
        const int q  = lane >> 4;
        const int nn = lane & 15;
        #pragma unroll
        for (int t = 0; t < 4; ++t) {
            const float* wr = w0 + (t * 16 + nn) * 32 + q * 8;
            short8 f;
            #pragma unroll
            for (int e = 0; e < 8; ++e) f[e] = (short)f2bf(wr[e]);
            *(short8*)(wlds + ((0 + t) * 64 + lane) * 16) = f;
        }
        #pragma unroll
        for (int s = 0; s < 2; ++s)
            #pragma unroll
            for (int t = 0; t < 4; ++t) {
                const float* wr1 = w1 + (t * 16 + nn) * 64 + s * 32 + q * 8;
                const float* wr2 = w2 + (t * 16 + nn) * 64 + s * 32 + q * 8;
                short8 f1, f2;
                #pragma unroll
                for (int e = 0; e < 8; ++e) {
                    f1[e] = (short)f2bf(wr1[e]);
                    f2[e] = (short)f2bf(wr2[e]);
                }
                *(short8*)(wlds + (( 4 + s * 4 + t) * 64 + lane) * 16) = f1;
                *(short8*)(wlds + ((12 + s * 4 + t) * 64 + lane) * 16) = f2;
            }
        #pragma unroll
        for (int s = 0; s < 2; ++s) {
            short8 f;
            #pragma unroll
            for (int e = 0; e < 8; ++e)
                f[e] = (nn < 3) ? (short)f2bf(wout[nn * 64 + s * 32 + q * 8 + e])
                                : (short)0;
            *(short8*)(wlds + ((20 + s) * 64 + lane) * 16) = f;
        }
    }
}

template <int NT>
static __device__ __forceinline__
void mlp_run(const unsigned* __restrict__ featbf,  // [NLVL][N]
             const float*    __restrict__ bout,
             float*          __restrict__ out,
             const char* wlds, char* hbase,
             int N, int firstTile, int lane)
{
    const int q  = lane >> 4;
    const int nn = lane & 15;

    short8 w0f[4];
    #pragma unroll
    for (int t = 0; t < 4; ++t)
        w0f[t] = *(const short8*)(wlds + ((0 + t) * 64 + lane) * 16);
    short8 w1f[2][4];
    #pragma unroll
    for (int s = 0; s < 2; ++s)
        #pragma unroll
        for (int t = 0; t < 4; ++t)
            w1f[s][t] = *(const short8*)(wlds + ((4 + s * 4 + t) * 64 + lane) * 16);
    const float bias = (nn < 3) ? bout[nn] : 0.0f;

    int idx0 = 0;   // always 0; laundered per tile (see TILE_BODY)

    unsigned ufA[4], ufB[4];
    {
        const int pA = (firstTile * 16 < N) ? (firstTile * 16 + nn) : 0;
        const int pB = ((firstTile + 1) * 16 < N) ? ((firstTile + 1) * 16 + nn) : 0;
        #pragma unroll
        for (int v = 0; v < 4; ++v) {
            ufA[v] = featbf[(size_t)(q * 4 + v) * N + pA];
            ufB[v] = featbf[(size_t)(q * 4 + v) * N + pB];
        }
    }

    for (int it = 0; it < NT; it += 2) {
        const int p0A = (firstTile + it) * 16;
        if (p0A >= N) break;

        short8 a0A;
        #pragma unroll
        for (int v = 0; v < 4; ++v) {
            a0A[2 * v]     = (short)(ufA[v] & 0xffffu);
            a0A[2 * v + 1] = (short)(ufA[v] >> 16);
        }
        {
            const int p0n = (firstTile + it + 2) * 16;
            const bool more = (it + 2 < NT) && (p0n < N);
            const int pn = more ? (p0n + nn) : 0;
            #pragma unroll
            for (int v = 0; v < 4; ++v)
                ufA[v] = featbf[(size_t)(q * 4 + v) * N + pn];
        }
        TILE_BODY(p0A, a0A)

        const int p0B = (firstTile + it + 1) * 16;
        if (p0B < N && it + 1 < NT) {
            short8 a0B;
            #pragma unroll
            for (int v = 0; v < 4; ++v) {
                a0B[2 * v]     = (short)(ufB[v] & 0xffffu);
                a0B[2 * v + 1] = (short)(ufB[v] >> 16);
            }
            {
                const int p0n = (firstTile + it + 3) * 16;
                const bool more = (it + 3 < NT) && (p0n < N);
                const int pn = more ? (p0n + nn) : 0;
                #pragma unroll
                for (int v = 0; v < 4; ++v)
                    ufB[v] = featbf[(size_t)(q * 4 + v) * N + pn];
            }
            TILE_BODY(p0B, a0B)
        }
    }
}

#define TILES_PER_WAVE 16

__global__ __launch_bounds__(256, 4)
void ingp_mlp_mfma(const unsigned* __restrict__ featbf,
                   const float*    __restrict__ w0,
                   const float*    __restrict__ w1,
                   const float*    __restrict__ w2,
                   const float*    __restrict__ wout,
                   const float*    __restrict__ bout,
                   float*          __restrict__ out,
                   int N)
{
    __shared__ char lds_raw[4 * 16 * 144];   // per-wave hidden staging (9216 B)
    __shared__ char wlds[22 * 64 * 16];      // all weight frags (22528 B)

    const int tid = (int)threadIdx.x;
    stage_wlds(w0, w1, w2, wout, wlds, tid);
    __syncthreads();

    const int wave = tid >> 6;
    const int lane = tid & 63;
    char* hbase = lds_raw + wave * (16 * 144);
    mlp_run<TILES_PER_WAVE>(featbf, bout, out, wlds, hbase, N,
                            ((int)blockIdx.x * 4 + wave) * TILES_PER_WAVE, lane);
}

// ---------------------------------------------------------------------------
// Fallback: fused scalar kernel (used only if ws is too small for features).
// ---------------------------------------------------------------------------
__global__ __launch_bounds__(256, 2)
void ingp_fused(const float4* __restrict__ x,
                const float2* __restrict__ table,
                const float*  __restrict__ w0,
                const float*  __restrict__ w1,
                const float*  __restrict__ w2,
                const float*  __restrict__ wout,
                const float*  __restrict__ bout,
                float*        __restrict__ out,
                int N, ResArr res)
{
    const int n = blockIdx.x * blockDim.x + threadIdx.x;
    if (n >= N) return;

    const float4 xv = x[n];
    const float px[4] = {xv.x, xv.y, xv.z, xv.w};

    float h1[64];
    #pragma unroll
    for (int j = 0; j < 64; ++j) h1[j] = 0.0f;

    float a0p = 0.0f, a1p = 0.0f;

    #pragma unroll 1
    for (int l = 0; l < NLVL; ++l) {
        int   rm[4], bi[4];
        float fr[4], om[4];
        #pragma unroll
        for (int d = 0; d < 4; ++d) {
            const int r = res.m1[l * 4 + d];
            rm[d] = r;
            const float pos = px[d] * (float)r;
            const float fb  = floorf(pos);
            fr[d] = pos - fb;
            om[d] = 1.0f - fr[d];
            bi[d] = (int)fb;
        }
        const float2* tl = table + (size_t)l * TSZ;

        float2 fv[16];
        float  wt[16];
        #pragma unroll
        for (int c = 0; c < 16; ++c) {
            int c0 = bi[0] + ( c       & 1);
            int c1 = bi[1] + ((c >> 1) & 1);
            int c2 = bi[2] + ((c >> 2) & 1);
            int c3 = bi[3] + ((c >> 3) & 1);
            c0 = min(max(c0, 0), rm[0]);
            c1 = min(max(c1, 0), rm[1]);
            c2 = min(max(c2, 0), rm[2]);
            c3 = min(max(c3, 0), rm[3]);
            const unsigned hh = (unsigned)c0
                              ^ ((unsigned)c1 * 2654435761u)
                              ^ ((unsigned)c2 * 805459861u)
                              ^ ((unsigned)c3 * 3674653429u);
            fv[c] = tl[hh & TMASK];
            float w = ( c       & 1) ? fr[0] : om[0];
            w      *= ((c >> 1) & 1) ? fr[1] : om[1];
            w      *= ((c >> 2) & 1) ? fr[2] : om[2];
            w      *= ((c >> 3) & 1) ? fr[3] : om[3];
            wt[c] = w;
        }
        {
            const int lp = (l == 0) ? 0 : (l - 1);
            const float* w0c = w0 + 2 * lp;
            #pragma unroll
            for (int j = 0; j < 64; ++j)
                h1[j] = fmaf(w0c[j * 32], a0p, fmaf(w0c[j * 32 + 1], a1p, h1[j]));
        }
        float a0 = 0.0f, a1 = 0.0f;
        #pragma unroll
        for (int c = 0; c < 16; ++c) {
            a0 = fmaf(wt[c], fv[c].x, a0);
            a1 = fmaf(wt[c], fv[c].y, a1);
        }
        a0p = a0; a1p = a1;
    }
    {
        const float* w0c = w0 + 2 * (NLVL - 1);
        #pragma unroll
        for (int j = 0; j < 64; ++j)
            h1[j] = fmaf(w0c[j * 32], a0p, fmaf(w0c[j * 32 + 1], a1p, h1[j]));
    }
    #pragma unroll
    for (int j = 0; j < 64; ++j) h1[j] = fmaxf(h1[j], 0.0f);

    float h2[64];
    #pragma unroll
    for (int j = 0; j < 64; ++j) {
        float acc = 0.0f;
        const float* wr = w1 + j * 64;
        #pragma unroll
        for (int i = 0; i < 64; ++i) acc = fmaf(wr[i], h1[i], acc);
        h2[j] = fmaxf(acc, 0.0f);
    }
    float h3[64];
    #pragma unroll
    for (int j = 0; j < 64; ++j) {
        float acc = 0.0f;
        const float* wr = w2 + j * 64;
        #pragma unroll
        for (int i = 0; i < 64; ++i) acc = fmaf(wr[i], h2[i], acc);
        h3[j] = fmaxf(acc, 0.0f);
    }
    float o[3];
    #pragma unroll
    for (int k = 0; k < 3; ++k) {
        float acc = bout[k];
        const float* wr = wout + k * 64;
        #pragma unroll
        for (int i = 0; i < 64; ++i) acc = fmaf(wr[i], h3[i], acc);
        o[k] = acc;
    }
    out[n * 3 + 0] = o[0];
    out[n * 3 + 1] = o[1];
    out[n * 3 + 2] = o[2];
}

extern "C" void kernel_launch(void* const* d_in, const int* in_sizes, int n_in,
                              void* d_out, int out_size, void* d_ws, size_t ws_size,
                              hipStream_t stream) {
    (void)n_in; (void)out_size;

    const float* x     = (const float*)d_in[0];
    const float* table = (const float*)d_in[1];
    const float* w0    = (const float*)d_in[2];
    const float* w1    = (const float*)d_in[3];
    const float* w2    = (const float*)d_in[4];
    const float* wout  = (const float*)d_in[5];
    const float* bout  = (const float*)d_in[6];
    float* out = (float*)d_out;

    const int N = in_sizes[0] / 4;

    // Replicate numpy's float64 resolution computation bit-for-bit (same
    // glibc pow). Levels 5/10/15 of dim 3 sit on exact integer boundaries
    // (8^(5/15)==2), so floor() must see the same double as numpy produced.
    ResArr res;
    for (int d = 0; d < 4; ++d) {
        const double minr = 16.0;
        const double maxr = (d == 3) ? 128.0 : 256.0;
        const double growth = pow(maxr / minr, 1.0 / (double)(NLVL - 1));
        for (int l = 0; l < NLVL; ++l) {
            const int r = (int)floor(minr * pow(growth, (double)l));
            res.m1[l * 4 + d] = r - 1;
        }
    }

    const size_t tblBytes  = (size_t)NLVL * TSZ * sizeof(unsigned);      // 32 MiB
    const size_t featBytes = (size_t)NLVL * (size_t)N * sizeof(unsigned);
    const int chunksPerLevel = (N + 255) / 256;
    const int totalUnits     = NLVL * chunksPerLevel;

    const int tiles  = (N + 15) / 16;
    const int waves  = (tiles + TILES_PER_WAVE - 1) / TILES_PER_WAVE;
    const int blocks = (waves + 3) / 4;

    // Probe cooperative-launch support + co-residency capacity once.
    static int s_coopGrid = -2;   // -2 = unprobed, 0 = unsupported, >0 = grid
    if (s_coopGrid == -2) {
        s_coopGrid = 0;
        hipDeviceProp_t prop;
        if (hipGetDeviceProperties(&prop, 0) == hipSuccess && prop.cooperativeLaunch) {
            int maxB = 0;
            if (hipOccupancyMaxActiveBlocksPerMultiprocessor(
                    &maxB, (const void*)ingp_cvt_encode, 256, 0) == hipSuccess &&
                maxB > 0) {
                long long cap = (long long)maxB * prop.multiProcessorCount;
                if (cap > 2048) cap = 2048;
                s_coopGrid = (int)cap;
            }
        }
    }

    if (ws_size >= tblBytes + featBytes + 256) {
        unsigned* tblbf    = (unsigned*)d_ws;
        unsigned* featbf   = (unsigned*)((char*)d_ws + tblBytes);
        unsigned* qcounter = (unsigned*)((char*)d_ws + tblBytes + featBytes);

        bool launched = false;
        if (s_coopGrid > 0) {
            const float4* x4 = (const float4*)x;
            const float4* t4 = (const float4*)table;
            int N_ = N, cpl_ = chunksPerLevel, tu_ = totalUnits;
            void* args[] = { (void*)&x4, (void*)&t4, (void*)&tblbf, (void*)&featbf,
                             (void*)&qcounter,
                             (void*)&N_, (void*)&cpl_, (void*)&tu_, (void*)&res };
            hipError_t err = hipLaunchCooperativeKernel(
                (const void*)ingp_cvt_encode, dim3(s_coopGrid), dim3(256),
                args, 0, stream);
            if (err == hipSuccess) {
                launched = true;
            } else {
                s_coopGrid = 0;   // don't retry on later calls
            }
        }
        if (!launched) {
            hipLaunchKernelGGL(cvt_table, dim3(2048), dim3(256), 0, stream,
                               (const float4*)table, (uint2*)tblbf,
                               (int)(NLVL * TSZ / 2));
            hipLaunchKernelGGL(ingp_encode_bf16, dim3(totalUnits), dim3(256),
                               0, stream, (const float4*)x, tblbf,
                               featbf, N, chunksPerLevel, res);
        }

        hipLaunchKernelGGL(ingp_mlp_mfma, dim3(blocks), dim3(256), 0, stream,
                           featbf, w0, w1, w2, wout, bout, out, N);
    } else if (ws_size >= featBytes) {
        unsigned* featbf = (unsigned*)d_ws;
        hipLaunchKernelGGL(ingp_encode_f32, dim3(totalUnits), dim3(256),
                           0, stream, (const float4*)x, (const float2*)table,
                           featbf, N, chunksPerLevel, res);

        hipLaunchKernelGGL(ingp_mlp_mfma, dim3(blocks), dim3(256), 0, stream,
                           featbf, w0, w1, w2, wout, bout, out, N);
    } else {
        hipLaunchKernelGGL(ingp_fused, dim3((N + 255) / 256), dim3(256), 0, stream,
                           (const float4*)x, (const float2*)table,
                           w0, w1, w2, wout, bout, out, N, res);
    }
}

// Round 9
// 704.242 us; speedup vs baseline: 1.6381x; 1.6113x over previous
//
#include <hip/hip_runtime.h>
#include <math.h>

#define NLVL  16
#define TSZ   (1u << 19)
#define TMASK (TSZ - 1u)

struct ResArr { int m1[NLVL * 4]; };  // per level, per dim: res-1

typedef short  short8  __attribute__((ext_vector_type(8)));
typedef float  float4v __attribute__((ext_vector_type(4)));

static __device__ __forceinline__ unsigned short f2bf(float f) {
    unsigned u = __float_as_uint(f);
    return (unsigned short)((u + 0x7fffu + ((u >> 16) & 1u)) >> 16);  // RNE
}

// ---------------------------------------------------------------------------
// Table conversion: f32 pairs (8B/entry) -> packed bf16 pairs (4B/entry).
// ---------------------------------------------------------------------------
__global__ __launch_bounds__(256)
void cvt_table(const float4* __restrict__ t, uint2* __restrict__ o, int totalPairs)
{
    for (int i = blockIdx.x * 256 + (int)threadIdx.x; i < totalPairs;
         i += gridDim.x * 256) {
        const float4 e = t[i];
        o[i] = make_uint2((unsigned)f2bf(e.x) | ((unsigned)f2bf(e.y) << 16),
                          (unsigned)f2bf(e.z) | ((unsigned)f2bf(e.w) << 16));
    }
}

// ---------------------------------------------------------------------------
// Encode, bf16-table version (verified r2-r6: 575-581 us, ~96% of the L2
// request-service roofline at ~10 req/point-level).
// SESSION INVARIANTS (counter-proven, do not revisit):
//  - DO NOT merge encode with the MLP in one kernel image: shared regalloc
//    caps encode occupancy / spills (r1: +150 us, r5: +2450 us).
//  - DO NOT replace the HW dispatcher with persistent blocks: both
//    grid-stride (r7) and atomic-queue (r8) widen the concurrent unit
//    window past per-XCD L2 capacity -> FETCH 234MB -> 0.9-3.2GB.
//    Level-major locality REQUIRES the in-order narrow dispatch window.
// ---------------------------------------------------------------------------
static __device__ __forceinline__
void encode_point_bf16(const float4*   __restrict__ x,
                       const unsigned* __restrict__ tbl,     // [NLVL][TSZ] bf16 pairs
                       unsigned*       __restrict__ featbf,  // [NLVL][N] bf16 pairs
                       int N, int l, int n, const ResArr& res)
{
    if (n >= N) return;

    const float4 xv = x[n];
    const float px[4] = {xv.x, xv.y, xv.z, xv.w};

    int   bi[4];
    float fr[4], om[4];
    #pragma unroll
    for (int d = 0; d < 4; ++d) {
        const int r = res.m1[l * 4 + d];       // wave-uniform -> scalar
        const float pos = px[d] * (float)r;
        const float fb  = floorf(pos);
        fr[d] = pos - fb;
        om[d] = 1.0f - fr[d];
        bi[d] = (int)fb;
    }
    const unsigned* tl  = tbl + (size_t)l * TSZ;
    const uint2*    tl2 = (const uint2*)tl;
    const uint4*    tl4 = (const uint4*)tl;

    unsigned hrest[8];
    #pragma unroll
    for (int p = 0; p < 8; ++p) {
        const int c1 = bi[1] + ( p       & 1);
        const int c2 = bi[2] + ((p >> 1) & 1);
        const int c3 = bi[3] + ((p >> 2) & 1);
        hrest[p] = ((unsigned)c1 * 2654435761u)
                 ^ ((unsigned)c2 * 805459861u)
                 ^ ((unsigned)c3 * 3674653429u);
    }

    const int b0 = bi[0];
    unsigned ea[8], eb[8];   // packed bf16 pairs: dim0-offset 0 / offset 1

    if ((b0 & 1) == 0) {
        // bi0 even: partner index = h ^ 1 -> one aligned 8B load per pair
        #pragma unroll
        for (int p = 0; p < 8; ++p) {
            const unsigned h = ((unsigned)b0 ^ hrest[p]) & TMASK;
            const uint2 q = tl2[h >> 1];
            ea[p] = (h & 1u) ? q.y : q.x;
            eb[p] = (h & 1u) ? q.x : q.y;
        }
    } else if ((b0 & 3) == 1) {
        // bi0 % 4 == 1: partner = h ^ 3 -> same aligned 16B group of 4 entries
        #pragma unroll
        for (int p = 0; p < 8; ++p) {
            const unsigned hA = ((unsigned)b0 ^ hrest[p]) & TMASK;
            const uint4 q = tl4[hA >> 2];
            const unsigned jA  = hA & 3u;
            const unsigned loA = (jA & 2u) ? q.z : q.x;
            const unsigned hiA = (jA & 2u) ? q.w : q.y;
            const unsigned loB = (jA & 2u) ? q.x : q.z;
            const unsigned hiB = (jA & 2u) ? q.y : q.w;
            ea[p] = (jA & 1u) ? hiA : loA;
            eb[p] = (jA & 1u) ? loB : hiB;
        }
    } else {
        // bi0 % 4 == 3: partner differs in >= 3 low bits -> two 4B loads
        #pragma unroll
        for (int p = 0; p < 8; ++p) {
            const unsigned hA = ((unsigned)b0       ^ hrest[p]) & TMASK;
            const unsigned hB = ((unsigned)(b0 + 1) ^ hrest[p]) & TMASK;
            ea[p] = tl[hA];
            eb[p] = tl[hB];
        }
    }

    float2 fv[16];   // fv[2p] = dim0-offset 0, fv[2p+1] = dim0-offset 1
    #pragma unroll
    for (int p = 0; p < 8; ++p) {
        fv[2 * p]     = make_float2(__uint_as_float(ea[p] << 16),
                                    __uint_as_float(ea[p] & 0xffff0000u));
        fv[2 * p + 1] = make_float2(__uint_as_float(eb[p] << 16),
                                    __uint_as_float(eb[p] & 0xffff0000u));
    }

    float wt[16];
    #pragma unroll
    for (int c = 0; c < 16; ++c) {
        float w = ( c       & 1) ? fr[0] : om[0];
        w      *= ((c >> 1) & 1) ? fr[1] : om[1];
        w      *= ((c >> 2) & 1) ? fr[2] : om[2];
        w      *= ((c >> 3) & 1) ? fr[3] : om[3];
        wt[c] = w;
    }

    float a0 = 0.0f, a1 = 0.0f;
    #pragma unroll
    for (int c = 0; c < 16; ++c) {           // same order as reference einsum
        a0 = fmaf(wt[c], fv[c].x, a0);
        a1 = fmaf(wt[c], fv[c].y, a1);
    }
    featbf[(size_t)l * N + n] = (unsigned)f2bf(a0) | ((unsigned)f2bf(a1) << 16);
}

__global__ __launch_bounds__(256, 4)
void ingp_encode_bf16(const float4*   __restrict__ x,
                      const unsigned* __restrict__ tbl,
                      unsigned*       __restrict__ featbf,
                      int N, int chunksPerLevel, ResArr res)
{
    const int l     = blockIdx.x / chunksPerLevel;
    const int chunk = blockIdx.x - l * chunksPerLevel;
    encode_point_bf16(x, tbl, featbf, N, l, chunk * 256 + (int)threadIdx.x, res);
}

// ---------------------------------------------------------------------------
// f32-table encode (fallback when ws can't hold the bf16 table copy).
// ---------------------------------------------------------------------------
static __device__ __forceinline__
void encode_point_f32(const float4* __restrict__ x,
                      const float2* __restrict__ table,
                      unsigned*     __restrict__ featbf,
                      int N, int l, int n, const ResArr& res)
{
    if (n >= N) return;

    const float4 xv = x[n];
    const float px[4] = {xv.x, xv.y, xv.z, xv.w};

    int   bi[4];
    float fr[4], om[4];
    #pragma unroll
    for (int d = 0; d < 4; ++d) {
        const int r = res.m1[l * 4 + d];
        const float pos = px[d] * (float)r;
        const float fb  = floorf(pos);
        fr[d] = pos - fb;
        om[d] = 1.0f - fr[d];
        bi[d] = (int)fb;
    }
    const float2* tl  = table + (size_t)l * TSZ;
    const float4* tl4 = (const float4*)tl;

    unsigned hrest[8];
    #pragma unroll
    for (int p = 0; p < 8; ++p) {
        const int c1 = bi[1] + ( p       & 1);
        const int c2 = bi[2] + ((p >> 1) & 1);
        const int c3 = bi[3] + ((p >> 2) & 1);
        hrest[p] = ((unsigned)c1 * 2654435761u)
                 ^ ((unsigned)c2 * 805459861u)
                 ^ ((unsigned)c3 * 3674653429u);
    }

    float2 fv[16];
    if ((bi[0] & 1) == 0) {
        #pragma unroll
        for (int p = 0; p < 8; ++p) {
            const unsigned h = ((unsigned)bi[0] ^ hrest[p]) & TMASK;
            const float4 q = tl4[h >> 1];
            const bool odd = (h & 1);
            fv[2 * p]     = odd ? make_float2(q.z, q.w) : make_float2(q.x, q.y);
            fv[2 * p + 1] = odd ? make_float2(q.x, q.y) : make_float2(q.z, q.w);
        }
    } else {
        #pragma unroll
        for (int p = 0; p < 8; ++p) {
            const unsigned hA = ((unsigned)bi[0]       ^ hrest[p]) & TMASK;
            const unsigned hB = ((unsigned)(bi[0] + 1) ^ hrest[p]) & TMASK;
            fv[2 * p]     = tl[hA];
            fv[2 * p + 1] = tl[hB];
        }
    }

    float wt[16];
    #pragma unroll
    for (int c = 0; c < 16; ++c) {
        float w = ( c       & 1) ? fr[0] : om[0];
        w      *= ((c >> 1) & 1) ? fr[1] : om[1];
        w      *= ((c >> 2) & 1) ? fr[2] : om[2];
        w      *= ((c >> 3) & 1) ? fr[3] : om[3];
        wt[c] = w;
    }

    float a0 = 0.0f, a1 = 0.0f;
    #pragma unroll
    for (int c = 0; c < 16; ++c) {
        a0 = fmaf(wt[c], fv[c].x, a0);
        a1 = fmaf(wt[c], fv[c].y, a1);
    }
    featbf[(size_t)l * N + n] = (unsigned)f2bf(a0) | ((unsigned)f2bf(a1) << 16);
}

__global__ __launch_bounds__(256, 4)
void ingp_encode_f32(const float4* __restrict__ x,
                     const float2* __restrict__ table,
                     unsigned*     __restrict__ featbf,
                     int N, int chunksPerLevel, ResArr res)
{
    const int l     = blockIdx.x / chunksPerLevel;
    const int chunk = blockIdx.x - l * chunksPerLevel;
    encode_point_f32(x, table, featbf, N, l, chunk * 256 + (int)threadIdx.x, res);
}

// ---------------------------------------------------------------------------
// MFMA MLP — r6-verified: all weight fragments staged through block-shared
// LDS (one wave loads; 4x fewer weight L2 requests/block), tilesPerWave=16
// (1024 blocks = one full round at 4 blocks/CU). w0f/w1f live in registers
// across the tile loop; w2/wout read from LDS per tile (idx0 laundered so
// LICM can't hoist them back into registers). Depth-2 feat prefetch ring.
// ---------------------------------------------------------------------------
#define TILE_BODY(P0, A0)                                                     \
{                                                                             \
    asm volatile("" : "+v"(idx0));   /* block LICM of the wlds reads below */ \
    float4v acc0[4];                                                          \
    _Pragma("unroll")                                                         \
    for (int t = 0; t < 4; ++t) {                                             \
        acc0[t] = (float4v){0.f, 0.f, 0.f, 0.f};                              \
        acc0[t] = __builtin_amdgcn_mfma_f32_16x16x32_bf16(A0, w0f[t], acc0[t], 0, 0, 0); \
    }                                                                         \
    _Pragma("unroll")                                                         \
    for (int t = 0; t < 4; ++t)                                               \
        _Pragma("unroll")                                                     \
        for (int r = 0; r < 4; ++r)                                           \
            *(unsigned short*)(hbase + (q * 4 + r) * 144 + (t * 16 + nn) * 2) = \
                f2bf(fmaxf(acc0[t][r], 0.0f));                                \
    short8 a1[2];                                                             \
    _Pragma("unroll")                                                         \
    for (int s = 0; s < 2; ++s)                                               \
        a1[s] = *(const short8*)(hbase + nn * 144 + s * 64 + q * 16);         \
    float4v acc1[4];                                                          \
    _Pragma("unroll")                                                         \
    for (int t = 0; t < 4; ++t) {                                             \
        acc1[t] = (float4v){0.f, 0.f, 0.f, 0.f};                              \
        _Pragma("unroll")                                                     \
        for (int s = 0; s < 2; ++s)                                           \
            acc1[t] = __builtin_amdgcn_mfma_f32_16x16x32_bf16(a1[s], w1f[s][t], acc1[t], 0, 0, 0); \
    }                                                                         \
    _Pragma("unroll")                                                         \
    for (int t = 0; t < 4; ++t)                                               \
        _Pragma("unroll")                                                     \
        for (int r = 0; r < 4; ++r)                                           \
            *(unsigned short*)(hbase + (q * 4 + r) * 144 + (t * 16 + nn) * 2) = \
                f2bf(fmaxf(acc1[t][r], 0.0f));                                \
    short8 a2[2];                                                             \
    _Pragma("unroll")                                                         \
    for (int s = 0; s < 2; ++s)                                               \
        a2[s] = *(const short8*)(hbase + nn * 144 + s * 64 + q * 16);         \
    float4v acc2[4];                                                          \
    _Pragma("unroll")                                                         \
    for (int t = 0; t < 4; ++t) {                                             \
        acc2[t] = (float4v){0.f, 0.f, 0.f, 0.f};                              \
        _Pragma("unroll")                                                     \
        for (int s = 0; s < 2; ++s) {                                         \
            const short8 w2x = *(const short8*)(wlds + ((12 + s * 4 + t) * 64 + lane) * 16 + idx0); \
            acc2[t] = __builtin_amdgcn_mfma_f32_16x16x32_bf16(a2[s], w2x, acc2[t], 0, 0, 0); \
        }                                                                     \
    }                                                                         \
    _Pragma("unroll")                                                         \
    for (int t = 0; t < 4; ++t)                                               \
        _Pragma("unroll")                                                     \
        for (int r = 0; r < 4; ++r)                                           \
            *(unsigned short*)(hbase + (q * 4 + r) * 144 + (t * 16 + nn) * 2) = \
                f2bf(fmaxf(acc2[t][r], 0.0f));                                \
    short8 a3[2];                                                             \
    _Pragma("unroll")                                                         \
    for (int s = 0; s < 2; ++s)                                               \
        a3[s] = *(const short8*)(hbase + nn * 144 + s * 64 + q * 16);         \
    float4v oc = (float4v){0.f, 0.f, 0.f, 0.f};                               \
    _Pragma("unroll")                                                         \
    for (int s = 0; s < 2; ++s) {                                             \
        const short8 wox = *(const short8*)(wlds + ((20 + s) * 64 + lane) * 16 + idx0); \
        oc = __builtin_amdgcn_mfma_f32_16x16x32_bf16(a3[s], wox, oc, 0, 0, 0); \
    }                                                                         \
    if (nn < 3) {                                                             \
        _Pragma("unroll")                                                     \
        for (int r = 0; r < 4; ++r) {                                         \
            const int pt = (P0) + q * 4 + r;                                  \
            if (pt < N) out[pt * 3 + nn] = oc[r] + bias;                      \
        }                                                                     \
    }                                                                         \
}

static __device__ __forceinline__
void stage_wlds(const float* __restrict__ w0, const float* __restrict__ w1,
                const float* __restrict__ w2, const float* __restrict__ wout,
                char* wlds, int tid)
{
    if (tid < 64) {
        const int lane = tid;
        const int q  = lane >> 4;
        const int nn = lane & 15;
        #pragma unroll
        for (int t = 0; t < 4; ++t) {
            const float* wr = w0 + (t * 16 + nn) * 32 + q * 8;
            short8 f;
            #pragma unroll
            for (int e = 0; e < 8; ++e) f[e] = (short)f2bf(wr[e]);
            *(short8*)(wlds + ((0 + t) * 64 + lane) * 16) = f;
        }
        #pragma unroll
        for (int s = 0; s < 2; ++s)
            #pragma unroll
            for (int t = 0; t < 4; ++t) {
                const float* wr1 = w1 + (t * 16 + nn) * 64 + s * 32 + q * 8;
                const float* wr2 = w2 + (t * 16 + nn) * 64 + s * 32 + q * 8;
                short8 f1, f2;
                #pragma unroll
                for (int e = 0; e < 8; ++e) {
                    f1[e] = (short)f2bf(wr1[e]);
                    f2[e] = (short)f2bf(wr2[e]);
                }
                *(short8*)(wlds + (( 4 + s * 4 + t) * 64 + lane) * 16) = f1;
                *(short8*)(wlds + ((12 + s * 4 + t) * 64 + lane) * 16) = f2;
            }
        #pragma unroll
        for (int s = 0; s < 2; ++s) {
            short8 f;
            #pragma unroll
            for (int e = 0; e < 8; ++e)
                f[e] = (nn < 3) ? (short)f2bf(wout[nn * 64 + s * 32 + q * 8 + e])
                                : (short)0;
            *(short8*)(wlds + ((20 + s) * 64 + lane) * 16) = f;
        }
    }
}

template <int NT>
static __device__ __forceinline__
void mlp_run(const unsigned* __restrict__ featbf,  // [NLVL][N]
             const float*    __restrict__ bout,
             float*          __restrict__ out,
             const char* wlds, char* hbase,
             int N, int firstTile, int lane)
{
    const int q  = lane >> 4;
    const int nn = lane & 15;

    // w0/w1 fragments: read ONCE from LDS into registers (loop-invariant)
    short8 w0f[4];
    #pragma unroll
    for (int t = 0; t < 4; ++t)
        w0f[t] = *(const short8*)(wlds + ((0 + t) * 64 + lane) * 16);
    short8 w1f[2][4];
    #pragma unroll
    for (int s = 0; s < 2; ++s)
        #pragma unroll
        for (int t = 0; t < 4; ++t)
            w1f[s][t] = *(const short8*)(wlds + ((4 + s * 4 + t) * 64 + lane) * 16);
    const float bias = (nn < 3) ? bout[nn] : 0.0f;

    int idx0 = 0;   // always 0; laundered per tile (see TILE_BODY)

    // ---- prologue: prefetch tiles 0 and 1 ----
    unsigned ufA[4], ufB[4];
    {
        const int pA = (firstTile * 16 < N) ? (firstTile * 16 + nn) : 0;
        const int pB = ((firstTile + 1) * 16 < N) ? ((firstTile + 1) * 16 + nn) : 0;
        #pragma unroll
        for (int v = 0; v < 4; ++v) {
            ufA[v] = featbf[(size_t)(q * 4 + v) * N + pA];
            ufB[v] = featbf[(size_t)(q * 4 + v) * N + pB];
        }
    }

    for (int it = 0; it < NT; it += 2) {
        const int p0A = (firstTile + it) * 16;
        if (p0A >= N) break;

        short8 a0A;
        #pragma unroll
        for (int v = 0; v < 4; ++v) {
            a0A[2 * v]     = (short)(ufA[v] & 0xffffu);
            a0A[2 * v + 1] = (short)(ufA[v] >> 16);
        }
        {
            const int p0n = (firstTile + it + 2) * 16;
            const bool more = (it + 2 < NT) && (p0n < N);
            const int pn = more ? (p0n + nn) : 0;
            #pragma unroll
            for (int v = 0; v < 4; ++v)
                ufA[v] = featbf[(size_t)(q * 4 + v) * N + pn];
        }
        TILE_BODY(p0A, a0A)

        const int p0B = (firstTile + it + 1) * 16;
        if (p0B < N && it + 1 < NT) {
            short8 a0B;
            #pragma unroll
            for (int v = 0; v < 4; ++v) {
                a0B[2 * v]     = (short)(ufB[v] & 0xffffu);
                a0B[2 * v + 1] = (short)(ufB[v] >> 16);
            }
            {
                const int p0n = (firstTile + it + 3) * 16;
                const bool more = (it + 3 < NT) && (p0n < N);
                const int pn = more ? (p0n + nn) : 0;
                #pragma unroll
                for (int v = 0; v < 4; ++v)
                    ufB[v] = featbf[(size_t)(q * 4 + v) * N + pn];
            }
            TILE_BODY(p0B, a0B)
        }
    }
}

#define TILES_PER_WAVE 16

__global__ __launch_bounds__(256, 4)
void ingp_mlp_mfma(const unsigned* __restrict__ featbf,
                   const float*    __restrict__ w0,
                   const float*    __restrict__ w1,
                   const float*    __restrict__ w2,
                   const float*    __restrict__ wout,
                   const float*    __restrict__ bout,
                   float*          __restrict__ out,
                   int N)
{
    __shared__ char lds_raw[4 * 16 * 144];   // per-wave hidden staging (9216 B)
    __shared__ char wlds[22 * 64 * 16];      // all weight frags (22528 B)

    const int tid = (int)threadIdx.x;
    stage_wlds(w0, w1, w2, wout, wlds, tid);
    __syncthreads();

    const int wave = tid >> 6;
    const int lane = tid & 63;
    char* hbase = lds_raw + wave * (16 * 144);
    mlp_run<TILES_PER_WAVE>(featbf, bout, out, wlds, hbase, N,
                            ((int)blockIdx.x * 4 + wave) * TILES_PER_WAVE, lane);
}

// ---------------------------------------------------------------------------
// Fallback: fused scalar kernel (used only if ws is too small for features).
// ---------------------------------------------------------------------------
__global__ __launch_bounds__(256, 2)
void ingp_fused(const float4* __restrict__ x,
                const float2* __restrict__ table,
                const float*  __restrict__ w0,
                const float*  __restrict__ w1,
                const float*  __restrict__ w2,
                const float*  __restrict__ wout,
                const float*  __restrict__ bout,
                float*        __restrict__ out,
                int N, ResArr res)
{
    const int n = blockIdx.x * blockDim.x + threadIdx.x;
    if (n >= N) return;

    const float4 xv = x[n];
    const float px[4] = {xv.x, xv.y, xv.z, xv.w};

    float h1[64];
    #pragma unroll
    for (int j = 0; j < 64; ++j) h1[j] = 0.0f;

    float a0p = 0.0f, a1p = 0.0f;

    #pragma unroll 1
    for (int l = 0; l < NLVL; ++l) {
        int   rm[4], bi[4];
        float fr[4], om[4];
        #pragma unroll
        for (int d = 0; d < 4; ++d) {
            const int r = res.m1[l * 4 + d];
            rm[d] = r;
            const float pos = px[d] * (float)r;
            const float fb  = floorf(pos);
            fr[d] = pos - fb;
            om[d] = 1.0f - fr[d];
            bi[d] = (int)fb;
        }
        const float2* tl = table + (size_t)l * TSZ;

        float2 fv[16];
        float  wt[16];
        #pragma unroll
        for (int c = 0; c < 16; ++c) {
            int c0 = bi[0] + ( c       & 1);
            int c1 = bi[1] + ((c >> 1) & 1);
            int c2 = bi[2] + ((c >> 2) & 1);
            int c3 = bi[3] + ((c >> 3) & 1);
            c0 = min(max(c0, 0), rm[0]);
            c1 = min(max(c1, 0), rm[1]);
            c2 = min(max(c2, 0), rm[2]);
            c3 = min(max(c3, 0), rm[3]);
            const unsigned hh = (unsigned)c0
                              ^ ((unsigned)c1 * 2654435761u)
                              ^ ((unsigned)c2 * 805459861u)
                              ^ ((unsigned)c3 * 3674653429u);
            fv[c] = tl[hh & TMASK];
            float w = ( c       & 1) ? fr[0] : om[0];
            w      *= ((c >> 1) & 1) ? fr[1] : om[1];
            w      *= ((c >> 2) & 1) ? fr[2] : om[2];
            w      *= ((c >> 3) & 1) ? fr[3] : om[3];
            wt[c] = w;
        }
        {
            const int lp = (l == 0) ? 0 : (l - 1);
            const float* w0c = w0 + 2 * lp;
            #pragma unroll
            for (int j = 0; j < 64; ++j)
                h1[j] = fmaf(w0c[j * 32], a0p, fmaf(w0c[j * 32 + 1], a1p, h1[j]));
        }
        float a0 = 0.0f, a1 = 0.0f;
        #pragma unroll
        for (int c = 0; c < 16; ++c) {
            a0 = fmaf(wt[c], fv[c].x, a0);
            a1 = fmaf(wt[c], fv[c].y, a1);
        }
        a0p = a0; a1p = a1;
    }
    {
        const float* w0c = w0 + 2 * (NLVL - 1);
        #pragma unroll
        for (int j = 0; j < 64; ++j)
            h1[j] = fmaf(w0c[j * 32], a0p, fmaf(w0c[j * 32 + 1], a1p, h1[j]));
    }
    #pragma unroll
    for (int j = 0; j < 64; ++j) h1[j] = fmaxf(h1[j], 0.0f);

    float h2[64];
    #pragma unroll
    for (int j = 0; j < 64; ++j) {
        float acc = 0.0f;
        const float* wr = w1 + j * 64;
        #pragma unroll
        for (int i = 0; i < 64; ++i) acc = fmaf(wr[i], h1[i], acc);
        h2[j] = fmaxf(acc, 0.0f);
    }
    float h3[64];
    #pragma unroll
    for (int j = 0; j < 64; ++j) {
        float acc = 0.0f;
        const float* wr = w2 + j * 64;
        #pragma unroll
        for (int i = 0; i < 64; ++i) acc = fmaf(wr[i], h2[i], acc);
        h3[j] = fmaxf(acc, 0.0f);
    }
    float o[3];
    #pragma unroll
    for (int k = 0; k < 3; ++k) {
        float acc = bout[k];
        const float* wr = wout + k * 64;
        #pragma unroll
        for (int i = 0; i < 64; ++i) acc = fmaf(wr[i], h3[i], acc);
        o[k] = acc;
    }
    out[n * 3 + 0] = o[0];
    out[n * 3 + 1] = o[1];
    out[n * 3 + 2] = o[2];
}

extern "C" void kernel_launch(void* const* d_in, const int* in_sizes, int n_in,
                              void* d_out, int out_size, void* d_ws, size_t ws_size,
                              hipStream_t stream) {
    (void)n_in; (void)out_size;

    const float* x     = (const float*)d_in[0];
    const float* table = (const float*)d_in[1];
    const float* w0    = (const float*)d_in[2];
    const float* w1    = (const float*)d_in[3];
    const float* w2    = (const float*)d_in[4];
    const float* wout  = (const float*)d_in[5];
    const float* bout  = (const float*)d_in[6];
    float* out = (float*)d_out;

    const int N = in_sizes[0] / 4;

    // Replicate numpy's float64 resolution computation bit-for-bit (same
    // glibc pow). Levels 5/10/15 of dim 3 sit on exact integer boundaries
    // (8^(5/15)==2), so floor() must see the same double as numpy produced.
    ResArr res;
    for (int d = 0; d < 4; ++d) {
        const double minr = 16.0;
        const double maxr = (d == 3) ? 128.0 : 256.0;
        const double growth = pow(maxr / minr, 1.0 / (double)(NLVL - 1));
        for (int l = 0; l < NLVL; ++l) {
            const int r = (int)floor(minr * pow(growth, (double)l));
            res.m1[l * 4 + d] = r - 1;
        }
    }

    const size_t tblBytes  = (size_t)NLVL * TSZ * sizeof(unsigned);      // 32 MiB
    const size_t featBytes = (size_t)NLVL * (size_t)N * sizeof(unsigned);
    const int chunksPerLevel = (N + 255) / 256;

    const int tiles  = (N + 15) / 16;
    const int waves  = (tiles + TILES_PER_WAVE - 1) / TILES_PER_WAVE;
    const int blocks = (waves + 3) / 4;

    if (ws_size >= tblBytes + featBytes) {
        unsigned* tblbf  = (unsigned*)d_ws;
        unsigned* featbf = (unsigned*)((char*)d_ws + tblBytes);

        hipLaunchKernelGGL(cvt_table, dim3(2048), dim3(256), 0, stream,
                           (const float4*)table, (uint2*)tblbf,
                           (int)(NLVL * TSZ / 2));

        hipLaunchKernelGGL(ingp_encode_bf16, dim3(NLVL * chunksPerLevel), dim3(256),
                           0, stream, (const float4*)x, tblbf,
                           featbf, N, chunksPerLevel, res);

        hipLaunchKernelGGL(ingp_mlp_mfma, dim3(blocks), dim3(256), 0, stream,
                           featbf, w0, w1, w2, wout, bout, out, N);
    } else if (ws_size >= featBytes) {
        unsigned* featbf = (unsigned*)d_ws;
        hipLaunchKernelGGL(ingp_encode_f32, dim3(NLVL * chunksPerLevel), dim3(256),
                           0, stream, (const float4*)x, (const float2*)table,
                           featbf, N, chunksPerLevel, res);

        hipLaunchKernelGGL(ingp_mlp_mfma, dim3(blocks), dim3(256), 0, stream,
                           featbf, w0, w1, w2, wout, bout, out, N);
    } else {
        hipLaunchKernelGGL(ingp_fused, dim3((N + 255) / 256), dim3(256), 0, stream,
                           (const float4*)x, (const float2*)table,
                           w0, w1, w2, wout, bout, out, N, res);
    }
}